// Round 2
// baseline (588.056 us; speedup 1.0000x reference)
//
#include <hip/hip_runtime.h>
#include <hip/hip_bf16.h>
#include <math.h>

// Problem constants: B=32, J=512, E=512, H=8, HD=64

typedef short short8 __attribute__((ext_vector_type(8)));
typedef float f32x4 __attribute__((ext_vector_type(4)));
typedef unsigned short u16;
typedef unsigned int u32;

__device__ __forceinline__ u16 f2b(float f) {
    union { float f; u32 u; } v; v.f = f;
    u32 r = (v.u + 0x7FFFu + ((v.u >> 16) & 1u)) >> 16;
    return (u16)r;
}
__device__ __forceinline__ float b2f(u16 u) {
    union { u32 u; float f; } v; v.u = ((u32)u) << 16;
    return v.f;
}

__device__ __forceinline__ void gl_lds16(const void* g, void* l) {
    __builtin_amdgcn_global_load_lds(
        (const __attribute__((address_space(1))) u32*)g,
        (__attribute__((address_space(3))) u32*)l, 16, 0, 0);
}

// ---------------- weight conversion ----------------
// Wqv: 1024x512 = [W_q rows | W_v rows]; Wcat: 512x1024 = [W_k | W_vproj]
__global__ __launch_bounds__(256) void convw(
    const float* __restrict__ Wqkv, const float* __restrict__ Wvp,
    const float* __restrict__ Wproj,
    u16* __restrict__ Wqv, u16* __restrict__ Wp, u16* __restrict__ Wcat)
{
    int i = blockIdx.x * 256 + threadIdx.x;      // 0..524287
    {
        int row = i >> 9;
        // q rows 0..511 -> Wqkv rows 0..511; v rows 512..1023 -> Wqkv rows 1024..1535
        size_t src = (size_t)i + (row < 512 ? 0 : 262144);
        Wqv[i] = f2b(Wqkv[src]);
    }
    {
        int n = i >> 10, c = i & 1023;
        float v = (c < 512) ? Wqkv[(size_t)(512 + n) * 512 + c]
                            : Wvp[(size_t)n * 512 + (c - 512)];
        Wcat[i] = f2b(v);
    }
    if (i < 262144) Wp[i] = f2b(Wproj[i]);
}

// ---------------- x_tan + A_cat (wave-per-row) ----------------
__global__ __launch_bounds__(256) void xtan_kernel(
    const float* __restrict__ x, const float* __restrict__ xvel,
    float* __restrict__ xtan_out, u16* __restrict__ Acat)
{
    int row = blockIdx.x * 4 + (threadIdx.x >> 6);
    int lane = threadIdx.x & 63;
    const float* xr = x + (size_t)row * 513;
    float a[8];
    float ss = 0.0f;
#pragma unroll
    for (int j = 0; j < 8; j++) { a[j] = xr[1 + j * 64 + lane]; ss += a[j] * a[j]; }
#pragma unroll
    for (int o = 32; o >= 1; o >>= 1) ss += __shfl_xor(ss, o);
    float x0 = fmaxf(xr[0], 1.0f + 1e-7f);
    float theta = acoshf(x0);
    float scl = theta / fmaxf(sqrtf(ss), 1e-7f);
    float* xo = xtan_out + (size_t)row * 512;
    u16* ac = Acat + (size_t)row * 1024;
#pragma unroll
    for (int j = 0; j < 8; j++) {
        float t = a[j] * scl;
        xo[j * 64 + lane] = t;
        ac[j * 64 + lane] = f2b(t);
    }
    const float* vr = xvel + (size_t)row * 513;
#pragma unroll
    for (int j = 0; j < 8; j++)
        ac[512 + j * 64 + lane] = f2b(vr[1 + j * 64 + lane]);
}

// ---------------- bf16 MFMA GEMM: C = A(MxK) * B(NxK)^T ----------------
// MODE 0: qv fused (N=1024): gn<512 -> qbuf, else vbuf, scatter [b][h][j][d]
// MODE 2: k (N=512): scatter [b][h][j][d]
// MODE 1: fp32 + bias (proj)
template <int MODE>
__global__ __launch_bounds__(256) void gemm_bt(
    const u16* __restrict__ A, int lda,
    const u16* __restrict__ Bm, int ldb, int K,
    u16* __restrict__ out_b, u16* __restrict__ out_b2,
    float* __restrict__ out_f, const float* __restrict__ bias)
{
    __shared__ u16 As[128 * 64];
    __shared__ u16 Bs[128 * 64];
    const int tid = threadIdx.x;
    const int w = tid >> 6, lane = tid & 63, l15 = lane & 15, quad = lane >> 4;
    const int m0 = blockIdx.y * 128, n0 = blockIdx.x * 128;
    const int wm = (w & 1) * 64, wn = (w >> 1) * 64;

    f32x4 acc[4][4];
#pragma unroll
    for (int i = 0; i < 4; i++)
#pragma unroll
        for (int j = 0; j < 4; j++) acc[i][j] = (f32x4)0.0f;

    for (int kt = 0; kt < K; kt += 64) {
#pragma unroll
        for (int i = 0; i < 4; i++) {
            int c = i * 256 + tid;
            int row = c >> 3, s = c & 7, gc = s ^ (row & 7);
            gl_lds16(&A[(size_t)(m0 + row) * lda + kt + gc * 8],
                     &As[(size_t)(i * 256 + (tid & ~63)) * 8]);
        }
#pragma unroll
        for (int i = 0; i < 4; i++) {
            int c = i * 256 + tid;
            int row = c >> 3, s = c & 7, gc = s ^ (row & 7);
            gl_lds16(&Bm[(size_t)(n0 + row) * ldb + kt + gc * 8],
                     &Bs[(size_t)(i * 256 + (tid & ~63)) * 8]);
        }
        __syncthreads();
#pragma unroll
        for (int kc = 0; kc < 2; kc++) {
            short8 af[4], bf[4];
#pragma unroll
            for (int t = 0; t < 4; t++) {
                int row = wm + t * 16 + l15;
                int slot = (kc * 4 + quad) ^ (row & 7);
                af[t] = *(const short8*)&As[row * 64 + slot * 8];
            }
#pragma unroll
            for (int t = 0; t < 4; t++) {
                int row = wn + t * 16 + l15;
                int slot = (kc * 4 + quad) ^ (row & 7);
                bf[t] = *(const short8*)&Bs[row * 64 + slot * 8];
            }
#pragma unroll
            for (int ti = 0; ti < 4; ti++)
#pragma unroll
                for (int tj = 0; tj < 4; tj++)
                    acc[ti][tj] = __builtin_amdgcn_mfma_f32_16x16x32_bf16(
                        af[ti], bf[tj], acc[ti][tj], 0, 0, 0);
        }
        __syncthreads();
    }

#pragma unroll
    for (int ti = 0; ti < 4; ti++)
#pragma unroll
        for (int tj = 0; tj < 4; tj++)
#pragma unroll
            for (int r = 0; r < 4; r++) {
                int gm = m0 + wm + ti * 16 + quad * 4 + r;   // row (A's m)
                int gn = n0 + wn + tj * 16 + l15;            // col (B's n)
                float vacc = acc[ti][tj][r];
                if (MODE == 1) {
                    out_f[(size_t)gm * 512 + gn] = vacc + bias[gn];
                } else {
                    int b = gm >> 9, j = gm & 511;
                    u16* dst;
                    int g;
                    if (MODE == 0) { dst = (gn < 512) ? out_b : out_b2; g = gn & 511; }
                    else { dst = out_b; g = gn; }
                    int h = g >> 6, d = g & 63;
                    dst[(((size_t)(b * 8 + h) * 512 + j) << 6) + d] = f2b(vacc);
                }
            }
}

// ---------------- v transpose: [bh][j][d] -> [bh][d][j] ----------------
__global__ __launch_bounds__(256) void vtrans(
    const u16* __restrict__ vb, u16* __restrict__ vT)
{
    __shared__ u16 tile[64][68];
    int bh = blockIdx.x >> 3, jt = blockIdx.x & 7;
    const u16* src = vb + (size_t)bh * 32768 + (size_t)jt * 4096;
#pragma unroll
    for (int i = 0; i < 4; i++) {
        int o = i * 1024 + threadIdx.x * 4;
        uint2 v = *(const uint2*)&src[o];
        int j = o >> 6, d = o & 63;
        *(uint2*)&tile[j][d] = v;
    }
    __syncthreads();
    u16* dst = vT + (size_t)bh * 32768 + jt * 64;
#pragma unroll
    for (int i = 0; i < 4; i++) {
        int o = i * 1024 + threadIdx.x * 4;
        int d = o >> 6, j0 = o & 63;
        u16 r0 = tile[j0][d], r1 = tile[j0 + 1][d];
        u16 r2 = tile[j0 + 2][d], r3 = tile[j0 + 3][d];
        uint2 pv;
        pv.x = (u32)r0 | ((u32)r1 << 16);
        pv.y = (u32)r2 | ((u32)r3 << 16);
        *(uint2*)&dst[(size_t)d * 512 + j0] = pv;
    }
}

// ---------------- fused attention (register softmax) ----------------
// block = one (b,h) + 32-row q tile. wave w covers cols [w*128,(w+1)*128)
__global__ __launch_bounds__(256) void attn_kernel(
    const u16* __restrict__ qb, const u16* __restrict__ kb,
    const u16* __restrict__ vT, const float* __restrict__ bias,
    float* __restrict__ attn_out, u16* __restrict__ z_bf)
{
    __shared__ u16 Sb[32 * 520];
    __shared__ float redM[32][4];
    __shared__ float redS[32][4];
    const int tid = threadIdx.x, w = tid >> 6, lane = tid & 63;
    const int l15 = lane & 15, quad = lane >> 4;
    const int bh = blockIdx.x >> 4, qt = blockIdx.x & 15;
    const int q0 = qt * 32;
    const u16* qp = qb + (size_t)bh * 32768;
    const u16* kp = kb + (size_t)bh * 32768;

    // ---- S = q k^T ----
    short8 qf[2][2];
#pragma unroll
    for (int ti = 0; ti < 2; ti++)
#pragma unroll
        for (int kc = 0; kc < 2; kc++)
            qf[ti][kc] = *(const short8*)&qp[(q0 + ti * 16 + l15) * 64 + kc * 32 + quad * 8];

    f32x4 sacc[2][8];
#pragma unroll
    for (int ti = 0; ti < 2; ti++)
#pragma unroll
        for (int kt = 0; kt < 8; kt++) sacc[ti][kt] = (f32x4)0.0f;

    const int kbase = w * 128;
#pragma unroll
    for (int kt = 0; kt < 8; kt++) {
        short8 kf[2];
        int n = kbase + kt * 16 + l15;
#pragma unroll
        for (int kc = 0; kc < 2; kc++)
            kf[kc] = *(const short8*)&kp[n * 64 + kc * 32 + quad * 8];
#pragma unroll
        for (int ti = 0; ti < 2; ti++)
#pragma unroll
            for (int kc = 0; kc < 2; kc++)
                sacc[ti][kt] = __builtin_amdgcn_mfma_f32_16x16x32_bf16(
                    qf[ti][kc], kf[kc], sacc[ti][kt], 0, 0, 0);
    }

    // ---- scale + bias (fp32, in registers) ----
    const float* bp = bias + (size_t)q0 * 512;
#pragma unroll
    for (int ti = 0; ti < 2; ti++)
#pragma unroll
        for (int kt = 0; kt < 8; kt++) {
            int col = kbase + kt * 16 + l15;
#pragma unroll
            for (int r = 0; r < 4; r++) {
                int row = ti * 16 + quad * 4 + r;
                sacc[ti][kt][r] = sacc[ti][kt][r] * 0.125f + bp[(size_t)row * 512 + col];
            }
        }

    // ---- row max: in-register over kt, shfl over l15, LDS across waves ----
    float mrow[2][4];
#pragma unroll
    for (int ti = 0; ti < 2; ti++) {
        f32x4 mv = sacc[ti][0];
#pragma unroll
        for (int kt = 1; kt < 8; kt++) {
#pragma unroll
            for (int r = 0; r < 4; r++) mv[r] = fmaxf(mv[r], sacc[ti][kt][r]);
        }
#pragma unroll
        for (int r = 0; r < 4; r++) {
            float v = mv[r];
            v = fmaxf(v, __shfl_xor(v, 1));
            v = fmaxf(v, __shfl_xor(v, 2));
            v = fmaxf(v, __shfl_xor(v, 4));
            v = fmaxf(v, __shfl_xor(v, 8));
            mrow[ti][r] = v;
        }
    }
    if (l15 == 0) {
#pragma unroll
        for (int ti = 0; ti < 2; ti++)
#pragma unroll
            for (int r = 0; r < 4; r++)
                redM[ti * 16 + quad * 4 + r][w] = mrow[ti][r];
    }
    __syncthreads();
#pragma unroll
    for (int ti = 0; ti < 2; ti++)
#pragma unroll
        for (int r = 0; r < 4; r++) {
            f32x4 rv = *(const f32x4*)redM[ti * 16 + quad * 4 + r];
            mrow[ti][r] = fmaxf(fmaxf(rv[0], rv[1]), fmaxf(rv[2], rv[3]));
        }

    // ---- exp (once, in registers) + row sum ----
    float srow[2][4];
#pragma unroll
    for (int ti = 0; ti < 2; ti++)
#pragma unroll
        for (int r = 0; r < 4; r++) srow[ti][r] = 0.0f;
#pragma unroll
    for (int ti = 0; ti < 2; ti++)
#pragma unroll
        for (int kt = 0; kt < 8; kt++)
#pragma unroll
            for (int r = 0; r < 4; r++) {
                float e = expf(sacc[ti][kt][r] - mrow[ti][r]);
                sacc[ti][kt][r] = e;
                srow[ti][r] += e;
            }
#pragma unroll
    for (int ti = 0; ti < 2; ti++)
#pragma unroll
        for (int r = 0; r < 4; r++) {
            float v = srow[ti][r];
            v += __shfl_xor(v, 1);
            v += __shfl_xor(v, 2);
            v += __shfl_xor(v, 4);
            v += __shfl_xor(v, 8);
            srow[ti][r] = v;
        }
    if (l15 == 0) {
#pragma unroll
        for (int ti = 0; ti < 2; ti++)
#pragma unroll
            for (int r = 0; r < 4; r++)
                redS[ti * 16 + quad * 4 + r][w] = srow[ti][r];
    }
    __syncthreads();
    float inv[2][4];
#pragma unroll
    for (int ti = 0; ti < 2; ti++)
#pragma unroll
        for (int r = 0; r < 4; r++) {
            f32x4 rv = *(const f32x4*)redS[ti * 16 + quad * 4 + r];
            inv[ti][r] = 1.0f / (rv[0] + rv[1] + rv[2] + rv[3]);
        }

    // ---- P: write attn fp32 to global, bf16 scatter into LDS for PV ----
    float* ap = attn_out + (size_t)bh * 262144 + (size_t)q0 * 512;
#pragma unroll
    for (int ti = 0; ti < 2; ti++)
#pragma unroll
        for (int kt = 0; kt < 8; kt++) {
            int col = kbase + kt * 16 + l15;
#pragma unroll
            for (int r = 0; r < 4; r++) {
                int row = ti * 16 + quad * 4 + r;
                float p = sacc[ti][kt][r] * inv[ti][r];
                ap[(size_t)row * 512 + col] = p;
                Sb[row * 520 + col] = f2b(p);
            }
        }
    __syncthreads();

    // ---- z = P @ V ----  wave w owns d-tile [w*16, w*16+16)
    const u16* vp = vT + (size_t)bh * 32768;
    f32x4 zacc[2];
    zacc[0] = (f32x4)0.0f; zacc[1] = (f32x4)0.0f;
    int n0 = w * 16;
#pragma unroll
    for (int kc = 0; kc < 16; kc++) {
        short8 bfv = *(const short8*)&vp[(size_t)(n0 + l15) * 512 + kc * 32 + quad * 8];
#pragma unroll
        for (int ti = 0; ti < 2; ti++) {
            short8 afp = *(const short8*)&Sb[(ti * 16 + l15) * 520 + kc * 32 + quad * 8];
            zacc[ti] = __builtin_amdgcn_mfma_f32_16x16x32_bf16(afp, bfv, zacc[ti], 0, 0, 0);
        }
    }
    int b = bh >> 3, h = bh & 7;
#pragma unroll
    for (int ti = 0; ti < 2; ti++)
#pragma unroll
        for (int r = 0; r < 4; r++) {
            int row = q0 + ti * 16 + quad * 4 + r;
            int d = n0 + l15;
            z_bf[((size_t)b * 512 + row) * 512 + h * 64 + d] = f2b(zacc[ti][r]);
        }
}

// ---------------- exp_map0 (wave-per-row) ----------------
__global__ __launch_bounds__(256) void expmap_kernel(
    const float* __restrict__ zp, float* __restrict__ out0)
{
    int row = blockIdx.x * 4 + (threadIdx.x >> 6);
    int lane = threadIdx.x & 63;
    const float* zr = zp + (size_t)row * 512;
    float a[8];
    float ss = 0.0f;
#pragma unroll
    for (int j = 0; j < 8; j++) { a[j] = zr[j * 64 + lane]; ss += a[j] * a[j]; }
#pragma unroll
    for (int o = 32; o >= 1; o >>= 1) ss += __shfl_xor(ss, o);
    float nrm = sqrtf(ss);
    float scl = sinhf(nrm) / fmaxf(nrm, 1e-7f);
    float* orow = out0 + (size_t)row * 513;
    if (lane == 0) orow[0] = coshf(nrm);
#pragma unroll
    for (int j = 0; j < 8; j++)
        orow[1 + j * 64 + lane] = a[j] * scl;
}

extern "C" void kernel_launch(void* const* d_in, const int* in_sizes, int n_in,
                              void* d_out, int out_size, void* d_ws, size_t ws_size,
                              hipStream_t stream) {
    const float* x     = (const float*)d_in[0];
    const float* xvel  = (const float*)d_in[1];
    const float* topo  = (const float*)d_in[2];
    const float* Wqkv  = (const float*)d_in[3];
    const float* Wvp   = (const float*)d_in[4];
    const float* Wproj = (const float*)d_in[5];
    const float* bproj = (const float*)d_in[6];

    float* out      = (float*)d_out;
    float* out_zman = out;                  // 32*512*513
    float* out_attn = out + 8404992;        // 32*8*512*512
    float* out_xtan = out + 75513856;       // 32*512*512

    char* ws = (char*)d_ws;
    u16*   Acat  = (u16*)ws;                      // 33,554,432 B
    u16*   Wqv   = (u16*)(ws + 33554432);         //  1,048,576
    u16*   Wcat  = (u16*)(ws + 34603008);         //  1,048,576
    u16*   Wp    = (u16*)(ws + 35651584);         //    524,288
    u16*   qbuf  = (u16*)(ws + 36175872);         // 16,777,216
    u16*   kbuf  = (u16*)(ws + 52953088);         // 16,777,216
    u16*   vbuf  = (u16*)(ws + 69730304);         // 16,777,216
    u16*   vT    = (u16*)(ws + 86507520);         // 16,777,216
    u16*   zbf   = (u16*)(ws + 103284736);        // 16,777,216
    float* zproj = (float*)(ws + 120061952);      // 33,554,432 (end 153,616,384)

    convw<<<2048, 256, 0, stream>>>(Wqkv, Wvp, Wproj, Wqv, Wp, Wcat);
    xtan_kernel<<<4096, 256, 0, stream>>>(x, xvel, out_xtan, Acat);

    gemm_bt<0><<<dim3(8, 128), 256, 0, stream>>>(Acat, 1024, Wqv, 512, 512,
                                                 qbuf, vbuf, nullptr, nullptr);
    gemm_bt<2><<<dim3(4, 128), 256, 0, stream>>>(Acat, 1024, Wcat, 1024, 1024,
                                                 kbuf, nullptr, nullptr, nullptr);

    vtrans<<<2048, 256, 0, stream>>>(vbuf, vT);

    attn_kernel<<<4096, 256, 0, stream>>>(qbuf, kbuf, vT, topo, out_attn, zbf);

    gemm_bt<1><<<dim3(4, 128), 256, 0, stream>>>(zbf, 512, Wp, 512, 512,
                                                 nullptr, nullptr, zproj, bproj);
    expmap_kernel<<<4096, 256, 0, stream>>>(zproj, out_zman);
}